// Round 3
// baseline (3841.764 us; speedup 1.0000x reference)
//
#include <hip/hip_runtime.h>
#include <hip/hip_bf16.h>

#define B_ 32
#define T_ 4096
#define H_ 512
#define A_ 512
#define C_ 32

// ---------------- prep: dpb[b,a] = dec[b]·W[a] + bias[a] ----------------
__global__ __launch_bounds__(256) void prep_fp32(
    const float* __restrict__ dec, const float* __restrict__ W,
    const float* __restrict__ bvec, float* __restrict__ dpb) {
    int id = blockIdx.x * 256 + threadIdx.x;   // [0, B*A)
    int b = id / A_, a = id % A_;
    const float* dr = dec + b * H_;
    const float* wr = W + (size_t)a * H_;
    float s = 0.f;
    #pragma unroll 8
    for (int h = 0; h < H_; ++h) s += dr[h] * wr[h];
    dpb[id] = s + bvec[a];
}

// ---------------- scores: pure fp32 VALU, LDS-tiled ----------------
__global__ __launch_bounds__(256) void scores_fp32(
    const float* __restrict__ enc, const float* __restrict__ align,
    const float* __restrict__ conv_w, const float* __restrict__ conv_b,
    const float* __restrict__ V, const float* __restrict__ U,
    const float* __restrict__ dpb, const float* __restrict__ wvec,
    float* __restrict__ scores) {
    const int t0 = blockIdx.x * 32;
    const int b = blockIdx.y;
    const int tid = threadIdx.x;
    const int trow = tid >> 5;     // 0..7
    const int tcol = tid & 31;     // 0..31

    __shared__ float sE[16][33];   // sE[kk][tt]: operand rows (enc / conv_feat)
    __shared__ float sV[16][513];  // sV[kk][a]:  operand cols (V / U)
    __shared__ float sred[32][33];

    float acc0[16], acc1[16], acc2[16], acc3[16];
    #pragma unroll
    for (int j = 0; j < 16; ++j) { acc0[j]=0.f; acc1[j]=0.f; acc2[j]=0.f; acc3[j]=0.f; }

    for (int kt = 0; kt < 34; ++kt) {
        const int k0 = kt * 16;
        __syncthreads();
        if (kt < 32) {
            #pragma unroll
            for (int i = 0; i < 2; ++i) {       // 512 sE elements
                int e = tid + i * 256;
                int tt = e >> 4, kk = e & 15;
                sE[kk][tt] = enc[((size_t)b * T_ + t0 + tt) * H_ + k0 + kk];
            }
            #pragma unroll
            for (int i = 0; i < 32; ++i) {      // 8192 sV elements
                int e = tid + i * 256;
                int a = e >> 4, kk = e & 15;
                sV[kk][a] = V[(size_t)a * H_ + k0 + kk];
            }
        } else {
            const int c0 = (kt - 32) * 16;
            #pragma unroll
            for (int i = 0; i < 2; ++i) {
                int e = tid + i * 256;
                int tt = e >> 4, kk = e & 15;
                int c = c0 + kk;
                int t = t0 + tt;
                float x0 = (t - 1 >= 0) ? align[b * T_ + t - 1] : 0.f;
                float x1 = align[b * T_ + t];
                float x2 = (t + 1 < T_) ? align[b * T_ + t + 1] : 0.f;
                sE[kk][tt] = conv_b[c] + conv_w[c * 3 + 0] * x0
                           + conv_w[c * 3 + 1] * x1 + conv_w[c * 3 + 2] * x2;
            }
            #pragma unroll
            for (int i = 0; i < 32; ++i) {
                int e = tid + i * 256;
                int a = e >> 4, kk = e & 15;
                sV[kk][a] = U[a * C_ + c0 + kk];
            }
        }
        __syncthreads();
        #pragma unroll
        for (int kk = 0; kk < 16; ++kk) {
            float e0 = sE[kk][trow * 4 + 0];
            float e1 = sE[kk][trow * 4 + 1];
            float e2 = sE[kk][trow * 4 + 2];
            float e3 = sE[kk][trow * 4 + 3];
            #pragma unroll
            for (int j = 0; j < 16; ++j) {
                float v = sV[kk][tcol + 32 * j];
                acc0[j] += e0 * v;
                acc1[j] += e1 * v;
                acc2[j] += e2 * v;
                acc3[j] += e3 * v;
            }
        }
    }

    // epilogue: tanh(acc + dpb)*w, partial over this thread's 16 a's
    float p0 = 0.f, p1 = 0.f, p2 = 0.f, p3 = 0.f;
    #pragma unroll
    for (int j = 0; j < 16; ++j) {
        int a = tcol + 32 * j;
        float dp = dpb[b * A_ + a];
        float ww = wvec[a];
        p0 += tanhf(acc0[j] + dp) * ww;
        p1 += tanhf(acc1[j] + dp) * ww;
        p2 += tanhf(acc2[j] + dp) * ww;
        p3 += tanhf(acc3[j] + dp) * ww;
    }
    sred[trow * 4 + 0][tcol] = p0;
    sred[trow * 4 + 1][tcol] = p1;
    sred[trow * 4 + 2][tcol] = p2;
    sred[trow * 4 + 3][tcol] = p3;
    __syncthreads();
    if (tid < 32) {
        float s = 0.f;
        #pragma unroll
        for (int c = 0; c < 32; ++c) s += sred[tid][c];
        scores[b * T_ + t0 + tid] = s;
    }
}

// ---------------- softmax over T per batch; writes fp32 alignment to d_out ----------------
__global__ __launch_bounds__(256) void softmax_k(
    const float* __restrict__ scores, float* __restrict__ out_align) {
    int b = blockIdx.x;
    int tid = threadIdx.x;
    __shared__ float redm[4];
    __shared__ float reds[4];
    float local[16];
    float mx = -1e30f;
    #pragma unroll
    for (int i = 0; i < 16; ++i) {
        float s = scores[b * T_ + tid + i * 256];
        local[i] = s;
        mx = fmaxf(mx, s);
    }
    for (int off = 32; off >= 1; off >>= 1) mx = fmaxf(mx, __shfl_xor(mx, off));
    if ((tid & 63) == 0) redm[tid >> 6] = mx;
    __syncthreads();
    mx = fmaxf(fmaxf(redm[0], redm[1]), fmaxf(redm[2], redm[3]));
    float sum = 0.f;
    #pragma unroll
    for (int i = 0; i < 16; ++i) { local[i] = __expf(local[i] - mx); sum += local[i]; }
    for (int off = 32; off >= 1; off >>= 1) sum += __shfl_xor(sum, off);
    if ((tid & 63) == 0) reds[tid >> 6] = sum;
    __syncthreads();
    sum = reds[0] + reds[1] + reds[2] + reds[3];
    float inv = 1.0f / sum;
    #pragma unroll
    for (int i = 0; i < 16; ++i)
        out_align[b * T_ + tid + i * 256] = local[i] * inv;
}

// ---------------- pout[b,chunk,h] = sum_{t in chunk} alpha * enc ----------------
__global__ __launch_bounds__(512) void pout_k(
    const float* __restrict__ enc, const float* __restrict__ alpha,
    float* __restrict__ pout) {
    int chunk = blockIdx.x;   // 0..7 (512 rows each)
    int b = blockIdx.y;
    int tid = threadIdx.x;    // h index, and staging index
    int t0 = chunk * 512;
    __shared__ float as[512];
    as[tid] = alpha[b * T_ + t0 + tid];
    __syncthreads();
    float acc = 0.f;
    const float* ep = enc + ((size_t)b * T_ + t0) * H_ + tid;
    #pragma unroll 4
    for (int t = 0; t < 512; ++t) acc += as[t] * ep[(size_t)t * H_];
    pout[((size_t)b * 8 + chunk) * H_ + tid] = acc;
}

__global__ __launch_bounds__(512) void combine_k(
    const float* __restrict__ pout, float* __restrict__ out) {
    int b = blockIdx.x; int h = threadIdx.x;
    float s = 0.f;
    #pragma unroll
    for (int c = 0; c < 8; ++c) s += pout[((size_t)b * 8 + c) * H_ + h];
    out[b * H_ + h] = s;
}

extern "C" void kernel_launch(void* const* d_in, const int* in_sizes, int n_in,
                              void* d_out, int out_size, void* d_ws, size_t ws_size,
                              hipStream_t stream) {
    const float* dec    = (const float*)d_in[0];
    const float* enc    = (const float*)d_in[1];
    const float* align  = (const float*)d_in[2];
    const float* conv_w = (const float*)d_in[3];
    const float* conv_b = (const float*)d_in[4];
    const float* W      = (const float*)d_in[5];
    const float* V      = (const float*)d_in[6];
    const float* U      = (const float*)d_in[7];
    const float* bvec   = (const float*)d_in[8];
    const float* wvec   = (const float*)d_in[9];
    float* out       = (float*)d_out;           // output[B,H] fp32
    float* out_align = out + B_ * H_;           // alignment[B,T] fp32

    char* ws = (char*)d_ws;
    float* dpb    = (float*)(ws);                 // 64 KB
    float* scores = (float*)(ws + (64 << 10));    // 512 KB
    float* pout   = (float*)(ws + (576 << 10));   // 512 KB

    prep_fp32<<<B_ * A_ / 256, 256, 0, stream>>>(dec, W, bvec, dpb);
    scores_fp32<<<dim3(T_ / 32, B_), 256, 0, stream>>>(enc, align, conv_w, conv_b,
                                                       V, U, dpb, wvec, scores);
    softmax_k<<<B_, 256, 0, stream>>>(scores, out_align);
    pout_k<<<dim3(8, B_), 512, 0, stream>>>(enc, out_align, pout);
    combine_k<<<B_, 512, 0, stream>>>(pout, out);
}

// Round 4
// 347.842 us; speedup vs baseline: 11.0446x; 11.0446x over previous
//
#include <hip/hip_runtime.h>
#include <hip/hip_bf16.h>

#define B_ 32
#define T_ 4096
#define H_ 512
#define A_ 512
#define C_ 32
#define KTOT 544            // H + C (conv folded in as K-extension)
#define NKG  (KTOT / 8)     // 68 k-groups of 8
#define NKS  (KTOT / 32)    // 17 MFMA k-steps

typedef float f32x4 __attribute__((ext_vector_type(4)));
typedef __bf16 bf16x8 __attribute__((ext_vector_type(8)));

// ---------------- prep: dpb = dec@W^T + b ; V,U -> unified bf16 fragment buffer ----
// Vsall[(k>>3)*A + a][e] for k in [0,544): k<512 from V, k>=512 from U.
__global__ __launch_bounds__(256) void prep_kernel(
    const float* __restrict__ dec, const float* __restrict__ W,
    const float* __restrict__ bvec, const float* __restrict__ V,
    const float* __restrict__ U,
    float* __restrict__ dpb, __bf16* __restrict__ Vsall) {
    int id = blockIdx.x * 256 + threadIdx.x;
    const int N1 = B_ * A_;          // 16384
    const int N2 = A_ * H_;          // 262144
    if (id < N1) {
        int b = id / A_, a = id % A_;
        const float* dr = dec + b * H_;
        const float* wr = W + (size_t)a * H_;
        float s = 0.f;
        #pragma unroll 8
        for (int h = 0; h < H_; ++h) s += dr[h] * wr[h];
        dpb[id] = s + bvec[a];
    } else if (id < N1 + N2) {
        int e = id - N1;
        int a = e >> 9, k = e & 511;
        Vsall[((k >> 3) * A_ + a) * 8 + (k & 7)] = (__bf16)V[(size_t)a * H_ + k];
    } else {
        int e = id - N1 - N2;        // 16384 U elements
        int a = e >> 5, c = e & 31;
        int k = H_ + c;
        Vsall[((k >> 3) * A_ + a) * 8 + (k & 7)] = (__bf16)U[a * C_ + c];
    }
}

// ---------------- fused scores: MFMA bf16, enc staged in LDS ----------------
// block = (32 t-rows, batch b), 4 waves; wave w covers A-cols [w*128, w*128+128)
__global__ __launch_bounds__(256) void scores_mfma(
    const float* __restrict__ enc, const float* __restrict__ align,
    const float* __restrict__ conv_w, const float* __restrict__ conv_b,
    const __bf16* __restrict__ Vsall, const float* __restrict__ dpb,
    const float* __restrict__ wvec, float* __restrict__ scores) {
    const int t0 = blockIdx.x * 32;
    const int b  = blockIdx.y;
    const int tid = threadIdx.x;
    const int lane = tid & 63, wid = tid >> 6;
    const int row0 = lane & 15;   // C/D col lane; A-frag row within 16
    const int kg   = lane >> 4;   // k-group 0..3 within a 32-k step
    const int wcol = wid * 128;

    // enc+conv staged as bf16 fragments: f = kgroup*32 + row, stored at g = f ^ ((f>>5)&7)
    __shared__ __bf16 Ebf[NKG * 32 * 8];   // 34816 B
    __shared__ float spart[4][32];

    // --- stage encoder rows (32 x 512 fp32 -> bf16), coalesced reads, swizzled writes ---
    const float* encb = enc + ((size_t)b * T_ + t0) * H_;
    #pragma unroll
    for (int c2 = 0; c2 < 8; ++c2) {
        int e = c2 * 2048 + tid * 8;          // e = row*512 + k0
        int row = e >> 9, k0 = e & 511;
        f32x4 lo = *reinterpret_cast<const f32x4*>(encb + e);
        f32x4 hi = *reinterpret_cast<const f32x4*>(encb + e + 4);
        bf16x8 v;
        v[0] = (__bf16)lo.x; v[1] = (__bf16)lo.y; v[2] = (__bf16)lo.z; v[3] = (__bf16)lo.w;
        v[4] = (__bf16)hi.x; v[5] = (__bf16)hi.y; v[6] = (__bf16)hi.z; v[7] = (__bf16)hi.w;
        int f = (k0 >> 3) * 32 + row;
        int g = f ^ ((f >> 5) & 7);
        *reinterpret_cast<bf16x8*>(&Ebf[g * 8]) = v;
    }
    // --- conv_feat rows as k-extension (k = 512..543) ---
    if (tid < 128) {
        int row = tid & 31, kgc = tid >> 5;
        int t = t0 + row;
        float x0 = (t > 0) ? align[b * T_ + t - 1] : 0.f;
        float x1 = align[b * T_ + t];
        float x2 = (t + 1 < T_) ? align[b * T_ + t + 1] : 0.f;
        bf16x8 v;
        #pragma unroll
        for (int e = 0; e < 8; ++e) {
            int c = kgc * 8 + e;
            float val = conv_b[c] + conv_w[c * 3 + 0] * x0 + conv_w[c * 3 + 1] * x1
                                  + conv_w[c * 3 + 2] * x2;
            v[e] = (__bf16)val;
        }
        int f = (64 + kgc) * 32 + row;
        int g = f ^ ((f >> 5) & 7);
        *reinterpret_cast<bf16x8*>(&Ebf[g * 8]) = v;
    }
    __syncthreads();

    f32x4 acc[2][8];
    #pragma unroll
    for (int m = 0; m < 2; ++m)
        #pragma unroll
        for (int n = 0; n < 8; ++n) acc[m][n] = (f32x4){0.f, 0.f, 0.f, 0.f};

    for (int ks = 0; ks < NKS; ++ks) {
        bf16x8 afrag[2];
        #pragma unroll
        for (int m = 0; m < 2; ++m) {
            int f = (ks * 4 + kg) * 32 + m * 16 + row0;
            int g = f ^ ((ks * 4 + kg) & 7);
            afrag[m] = *reinterpret_cast<const bf16x8*>(&Ebf[g * 8]);
        }
        const __bf16* vp = Vsall + (size_t)(ks * 4 + kg) * A_ * 8;
        #pragma unroll
        for (int n = 0; n < 8; ++n) {
            int col = wcol + n * 16 + row0;
            bf16x8 bfrag = *reinterpret_cast<const bf16x8*>(vp + col * 8);
            acc[0][n] = __builtin_amdgcn_mfma_f32_16x16x32_bf16(afrag[0], bfrag, acc[0][n], 0, 0, 0);
            acc[1][n] = __builtin_amdgcn_mfma_f32_16x16x32_bf16(afrag[1], bfrag, acc[1][n], 0, 0, 0);
        }
    }

    // epilogue: tanh(acc + dpb)*w, reduce over A
    float dval[8], wv[8];
    #pragma unroll
    for (int n = 0; n < 8; ++n) {
        int a = wcol + n * 16 + row0;
        dval[n] = dpb[b * A_ + a];
        wv[n]   = wvec[a];
    }
    #pragma unroll
    for (int m = 0; m < 2; ++m) {
        float rs[4] = {0.f, 0.f, 0.f, 0.f};
        #pragma unroll
        for (int n = 0; n < 8; ++n) {
            #pragma unroll
            for (int j = 0; j < 4; ++j) {
                float x = acc[m][n][j] + dval[n];
                rs[j] += tanhf(x) * wv[n];
            }
        }
        #pragma unroll
        for (int j = 0; j < 4; ++j) {
            float v = rs[j];
            v += __shfl_xor(v, 1);
            v += __shfl_xor(v, 2);
            v += __shfl_xor(v, 4);
            v += __shfl_xor(v, 8);
            if (row0 == 0) spart[wid][m * 16 + kg * 4 + j] = v;  // C/D row = kg*4+j
        }
    }
    __syncthreads();
    if (tid < 32) {
        float s = spart[0][tid] + spart[1][tid] + spart[2][tid] + spart[3][tid];
        scores[b * T_ + t0 + tid] = s;
    }
}

// ---------------- softmax over T per batch; fp32 alignment into d_out ----------------
__global__ __launch_bounds__(256) void softmax_k(
    const float* __restrict__ scores, float* __restrict__ out_align) {
    int b = blockIdx.x;
    int tid = threadIdx.x;
    __shared__ float redm[4];
    __shared__ float reds[4];
    float local[16];
    float mx = -1e30f;
    #pragma unroll
    for (int i = 0; i < 16; ++i) {
        float s = scores[b * T_ + tid + i * 256];
        local[i] = s;
        mx = fmaxf(mx, s);
    }
    for (int off = 32; off >= 1; off >>= 1) mx = fmaxf(mx, __shfl_xor(mx, off));
    if ((tid & 63) == 0) redm[tid >> 6] = mx;
    __syncthreads();
    mx = fmaxf(fmaxf(redm[0], redm[1]), fmaxf(redm[2], redm[3]));
    float sum = 0.f;
    #pragma unroll
    for (int i = 0; i < 16; ++i) { local[i] = __expf(local[i] - mx); sum += local[i]; }
    for (int off = 32; off >= 1; off >>= 1) sum += __shfl_xor(sum, off);
    if ((tid & 63) == 0) reds[tid >> 6] = sum;
    __syncthreads();
    sum = reds[0] + reds[1] + reds[2] + reds[3];
    float inv = 1.0f / sum;
    #pragma unroll
    for (int i = 0; i < 16; ++i)
        out_align[b * T_ + tid + i * 256] = local[i] * inv;
}

// ---------------- pout[b,chunk,h] = sum_{t in chunk} alpha * enc ----------------
__global__ __launch_bounds__(512) void pout_k(
    const float* __restrict__ enc, const float* __restrict__ alpha,
    float* __restrict__ pout) {
    int chunk = blockIdx.x;   // 0..7 (512 rows each)
    int b = blockIdx.y;
    int tid = threadIdx.x;
    int t0 = chunk * 512;
    __shared__ float as[512];
    as[tid] = alpha[b * T_ + t0 + tid];
    __syncthreads();
    float acc = 0.f;
    const float* ep = enc + ((size_t)b * T_ + t0) * H_ + tid;
    #pragma unroll 4
    for (int t = 0; t < 512; ++t) acc += as[t] * ep[(size_t)t * H_];
    pout[((size_t)b * 8 + chunk) * H_ + tid] = acc;
}

__global__ __launch_bounds__(512) void combine_k(
    const float* __restrict__ pout, float* __restrict__ out) {
    int b = blockIdx.x; int h = threadIdx.x;
    float s = 0.f;
    #pragma unroll
    for (int c = 0; c < 8; ++c) s += pout[((size_t)b * 8 + c) * H_ + h];
    out[b * H_ + h] = s;
}

extern "C" void kernel_launch(void* const* d_in, const int* in_sizes, int n_in,
                              void* d_out, int out_size, void* d_ws, size_t ws_size,
                              hipStream_t stream) {
    const float* dec    = (const float*)d_in[0];
    const float* enc    = (const float*)d_in[1];
    const float* align  = (const float*)d_in[2];
    const float* conv_w = (const float*)d_in[3];
    const float* conv_b = (const float*)d_in[4];
    const float* W      = (const float*)d_in[5];
    const float* V      = (const float*)d_in[6];
    const float* U      = (const float*)d_in[7];
    const float* bvec   = (const float*)d_in[8];
    const float* wvec   = (const float*)d_in[9];
    float* out       = (float*)d_out;           // output[B,H] fp32
    float* out_align = out + B_ * H_;           // alignment[B,T] fp32

    char* ws = (char*)d_ws;
    float*  dpb    = (float*)(ws);                   // 64 KB
    float*  scores = (float*)(ws + (64 << 10));      // 512 KB
    float*  pout   = (float*)(ws + (576 << 10));     // 512 KB
    __bf16* Vsall  = (__bf16*)(ws + (1088 << 10));   // 68*512*8*2 = 544 KB... (1.09 MB region)

    prep_kernel<<<(B_ * A_ + A_ * H_ + A_ * C_) / 256, 256, 0, stream>>>(
        dec, W, bvec, V, U, dpb, Vsall);
    scores_mfma<<<dim3(T_ / 32, B_), 256, 0, stream>>>(enc, align, conv_w, conv_b,
                                                       Vsall, dpb, wvec, scores);
    softmax_k<<<B_, 256, 0, stream>>>(scores, out_align);
    pout_k<<<dim3(8, B_), 512, 0, stream>>>(enc, out_align, pout);
    combine_k<<<B_, 512, 0, stream>>>(pout, out);
}